// Round 5
// baseline (340.372 us; speedup 1.0000x reference)
//
#include <hip/hip_runtime.h>

#define EMBED 1024
#define HEADS 8
#define DIM_HEAD 64
#define INNER 512
#define BATCH 16
#define SEQ 2048

// ws layout (floats):
#define WS_Q     0         // 512
#define WS_QKB   512       // 4096 uints = 8*1024 f16 (qk, pre-scaled by 0.125)
#define WS_ACC   4608      // 131072  (acc[16][8][1024], atomically accumulated)
#define WS_LG    135680    // 128     (l[16][8])
#define WS_OM    135808    // 8192    (om[16][512])

typedef _Float16 h2 __attribute__((ext_vector_type(2)));
union U2H { unsigned int u; h2 h; };

__device__ __forceinline__ h2 pk_f16(float a, float b) {
    return __builtin_bit_cast(h2, __builtin_amdgcn_cvt_pkrtz(a, b));
}

#if defined(__has_builtin)
#if __has_builtin(__builtin_amdgcn_fdot2)
#define FDOT2(a, b, c) __builtin_amdgcn_fdot2((a), (b), (c), false)
#endif
#endif
#ifndef FDOT2
__device__ __forceinline__ float fdot2_emul(h2 a, h2 b, float c) {
    return c + (float)a[0] * (float)b[0] + (float)a[1] * (float)b[1];
}
#define FDOT2(a, b, c) fdot2_emul((a), (b), (c))
#endif

// ---------------------------------------------------------------------------
// zero the atomic accumulators (accg + lg = 131200 floats = 32800 float4)
__global__ void ap_zero(float* __restrict__ p, int n4) {
    int i = blockIdx.x * blockDim.x + threadIdx.x;
    if (i < n4) ((float4*)p)[i] = make_float4(0.f, 0.f, 0.f, 0.f);
}

// ---------------------------------------------------------------------------
// f0a: q[i] = token . Wq[i]  (512 dots of len 1024). grid 64, block 256.
__global__ void ap_f0a_q(const float* __restrict__ token, const float* __restrict__ Wq,
                         float* __restrict__ q) {
    const int t = threadIdx.x;
    const int w = t >> 6, lane = t & 63;
    const int i0 = blockIdx.x * 8 + w * 2;
    const float4* tok4 = (const float4*)token;
    const float4* r0 = (const float4*)Wq + (long)i0 * 256;
    const float4* r1 = r0 + 256;
    float a0 = 0.f, a1 = 0.f;
#pragma unroll
    for (int k = 0; k < 4; ++k) {
        int e4 = k * 64 + lane;
        float4 tv = tok4[e4];
        float4 w0 = r0[e4];
        float4 w1 = r1[e4];
        a0 += tv.x * w0.x + tv.y * w0.y + tv.z * w0.z + tv.w * w0.w;
        a1 += tv.x * w1.x + tv.y * w1.y + tv.z * w1.z + tv.w * w1.w;
    }
#pragma unroll
    for (int off = 32; off; off >>= 1) {
        a0 += __shfl_xor(a0, off);
        a1 += __shfl_xor(a1, off);
    }
    if (lane == 0) { q[i0] = a0; q[i0 + 1] = a1; }
}

// ---------------------------------------------------------------------------
// f0b: qk[h][e] = 0.125 * sum_d q[h*64+d] * Wk[h*64+d][e], packed to f16 pairs.
// qkh[h*512 + e/2] = half2(qk[e], qk[e+1]).  grid 64 (h=blk>>3, ec=blk&7), block 128.
__global__ void ap_f0b_qk(const float* __restrict__ q, const float* __restrict__ Wkv,
                          unsigned int* __restrict__ qkh) {
    __shared__ float q_s[64];
    __shared__ float a_s[128];
    const int h = blockIdx.x >> 3, ec = blockIdx.x & 7;
    const int t = threadIdx.x;
    if (t < 64) q_s[t] = q[h * 64 + t];
    __syncthreads();
    const int e = ec * 128 + t;
    float a = 0.f;
#pragma unroll 8
    for (int d = 0; d < 64; ++d)
        a += q_s[d] * Wkv[(long)(h * 64 + d) * EMBED + e];
    a_s[t] = 0.125f * a;
    __syncthreads();
    if (t < 64) {
        U2H u;
        u.h = pk_f16(a_s[2 * t], a_s[2 * t + 1]);
        qkh[h * 512 + ec * 64 + t] = u.u;
    }
}

// ---------------------------------------------------------------------------
// F1: single pass over x. grid 1024 (b=blk>>6, slice=blk&63), block 256 = 4 waves.
// 32 rows/block, 4 tiles of 8 rows; wave computes sims for 2 rows (full e from
// registers, qk f16 in LDS, v_dot2), then after ONE barrier accumulates its
// 256-wide e-slice for all 8 heads from a global L2 re-read of the tile.
// Next tile's sim loads are register-prefetched; p_s double-buffered.
// exp without max-subtraction: |sim| < ~1 for this problem's scales.
__global__ __launch_bounds__(256, 3) void ap_f1(const float* __restrict__ x,
                                                const unsigned int* __restrict__ qkh,
                                                float* __restrict__ accg,
                                                float* __restrict__ lg) {
    __shared__ unsigned int qk_s[4096];          // 16 KB f16 qk
    __shared__ __align__(16) float p_s[2][8][8]; // double-buffered exp weights
    __shared__ float l_s[4][8];
    const int t = threadIdx.x;
    const int w = t >> 6, lane = t & 63, g = lane >> 3;
    const int b = blockIdx.x >> 6, slice = blockIdx.x & 63;

    ((uint4*)qk_s)[t]       = ((const uint4*)qkh)[t];
    ((uint4*)qk_s)[t + 256] = ((const uint4*)qkh)[t + 256];
    ((uint4*)qk_s)[t + 512] = ((const uint4*)qkh)[t + 512];
    ((uint4*)qk_s)[t + 768] = ((const uint4*)qkh)[t + 768];
    __syncthreads();

    const long rowbase = (long)b * SEQ + slice * 32;
    const float4* xg = (const float4*)x;

    float4 acc[8];
#pragma unroll
    for (int h = 0; h < 8; ++h) acc[h] = make_float4(0.f, 0.f, 0.f, 0.f);
    float lw = 0.f;

    // prefetch tile 0 sim rows (wave's 2 rows, full e)
    float4 xc0[4], xc1[4];
    {
        const float4* rp = xg + (rowbase + w * 2) * 256;
#pragma unroll
        for (int k = 0; k < 4; ++k) xc0[k] = rp[k * 64 + lane];
#pragma unroll
        for (int k = 0; k < 4; ++k) xc1[k] = rp[256 + k * 64 + lane];
    }

    for (int tile = 0; tile < 4; ++tile) {
        // prefetch next tile's sim rows
        float4 xn0[4], xn1[4];
        if (tile < 3) {
            const float4* rp = xg + (rowbase + (tile + 1) * 8 + w * 2) * 256;
#pragma unroll
            for (int k = 0; k < 4; ++k) xn0[k] = rp[k * 64 + lane];
#pragma unroll
            for (int k = 0; k < 4; ++k) xn1[k] = rp[256 + k * 64 + lane];
        }
        // early-issue acc loads for this tile (e-slice, L2-hot)
        float4 xa[8];
        {
            const float4* ap = xg + (rowbase + tile * 8) * 256 + w * 64 + lane;
#pragma unroll
            for (int r = 0; r < 8; ++r) xa[r] = ap[r * 256];
        }

        // sim compute on current rows (f16 dot2 against LDS qk)
        h2 c0[8], c1[8];
#pragma unroll
        for (int k = 0; k < 4; ++k) {
            c0[2 * k]     = pk_f16(xc0[k].x, xc0[k].y);
            c0[2 * k + 1] = pk_f16(xc0[k].z, xc0[k].w);
            c1[2 * k]     = pk_f16(xc1[k].x, xc1[k].y);
            c1[2 * k + 1] = pk_f16(xc1[k].z, xc1[k].w);
        }
        float s0[8], s1[8];
#pragma unroll
        for (int h = 0; h < 8; ++h) { s0[h] = 0.f; s1[h] = 0.f; }
#pragma unroll
        for (int k = 0; k < 4; ++k) {
#pragma unroll
            for (int h = 0; h < 8; ++h) {
                uint2 qu = *(const uint2*)&qk_s[h * 512 + k * 128 + lane * 2];
                U2H qa, qb; qa.u = qu.x; qb.u = qu.y;
                s0[h] = FDOT2(c0[2 * k], qa.h, s0[h]);
                s0[h] = FDOT2(c0[2 * k + 1], qb.h, s0[h]);
                s1[h] = FDOT2(c1[2 * k], qa.h, s1[h]);
                s1[h] = FDOT2(c1[2 * k + 1], qb.h, s1[h]);
            }
        }
        // 3 butterfly levels on all heads (reduce lane bits 5,4,3)
#pragma unroll
        for (int h = 0; h < 8; ++h) {
            s0[h] += __shfl_xor(s0[h], 32); s1[h] += __shfl_xor(s1[h], 32);
            s0[h] += __shfl_xor(s0[h], 16); s1[h] += __shfl_xor(s1[h], 16);
            s0[h] += __shfl_xor(s0[h], 8);  s1[h] += __shfl_xor(s1[h], 8);
        }
        // select head g per 8-lane group, finish reduction within the group
        float v0, v1;
        {
            float a0 = (g & 1) ? s0[1] : s0[0];
            float a1 = (g & 1) ? s0[3] : s0[2];
            float a2 = (g & 1) ? s0[5] : s0[4];
            float a3 = (g & 1) ? s0[7] : s0[6];
            float b0 = (g & 2) ? a1 : a0;
            float b1 = (g & 2) ? a3 : a2;
            v0 = (g & 4) ? b1 : b0;
            a0 = (g & 1) ? s1[1] : s1[0];
            a1 = (g & 1) ? s1[3] : s1[2];
            a2 = (g & 1) ? s1[5] : s1[4];
            a3 = (g & 1) ? s1[7] : s1[6];
            b0 = (g & 2) ? a1 : a0;
            b1 = (g & 2) ? a3 : a2;
            v1 = (g & 4) ? b1 : b0;
        }
        v0 += __shfl_xor(v0, 4); v1 += __shfl_xor(v1, 4);
        v0 += __shfl_xor(v0, 2); v1 += __shfl_xor(v1, 2);
        v0 += __shfl_xor(v0, 1); v1 += __shfl_xor(v1, 1);
        float p0 = __expf(v0), p1 = __expf(v1);
        lw += p0 + p1;
        if ((lane & 7) == 0) {
            p_s[tile & 1][w * 2][g] = p0;
            p_s[tile & 1][w * 2 + 1][g] = p1;
        }
        __syncthreads();

        // acc phase: wave's 256-wide e-slice, all 8 heads, 8 rows
#pragma unroll
        for (int r = 0; r < 8; ++r) {
            float4 pA = *(const float4*)&p_s[tile & 1][r][0];
            float4 pB = *(const float4*)&p_s[tile & 1][r][4];
            float4 xv = xa[r];
            acc[0].x += pA.x * xv.x; acc[0].y += pA.x * xv.y; acc[0].z += pA.x * xv.z; acc[0].w += pA.x * xv.w;
            acc[1].x += pA.y * xv.x; acc[1].y += pA.y * xv.y; acc[1].z += pA.y * xv.z; acc[1].w += pA.y * xv.w;
            acc[2].x += pA.z * xv.x; acc[2].y += pA.z * xv.y; acc[2].z += pA.z * xv.z; acc[2].w += pA.z * xv.w;
            acc[3].x += pA.w * xv.x; acc[3].y += pA.w * xv.y; acc[3].z += pA.w * xv.z; acc[3].w += pA.w * xv.w;
            acc[4].x += pB.x * xv.x; acc[4].y += pB.x * xv.y; acc[4].z += pB.x * xv.z; acc[4].w += pB.x * xv.w;
            acc[5].x += pB.y * xv.x; acc[5].y += pB.y * xv.y; acc[5].z += pB.y * xv.z; acc[5].w += pB.y * xv.w;
            acc[6].x += pB.z * xv.x; acc[6].y += pB.z * xv.y; acc[6].z += pB.z * xv.z; acc[6].w += pB.z * xv.w;
            acc[7].x += pB.w * xv.x; acc[7].y += pB.w * xv.y; acc[7].z += pB.w * xv.z; acc[7].w += pB.w * xv.w;
        }
        if (tile < 3) {
#pragma unroll
            for (int k = 0; k < 4; ++k) { xc0[k] = xn0[k]; xc1[k] = xn1[k]; }
        }
    }

    // global accumulation: lane's 4 e-floats × 8 heads
    float* base = accg + (long)(b * 8) * 1024 + w * 256 + lane * 4;
#pragma unroll
    for (int h = 0; h < 8; ++h) {
        atomicAdd(base + h * 1024 + 0, acc[h].x);
        atomicAdd(base + h * 1024 + 1, acc[h].y);
        atomicAdd(base + h * 1024 + 2, acc[h].z);
        atomicAdd(base + h * 1024 + 3, acc[h].w);
    }
    if ((lane & 7) == 0) l_s[w][g] = lw;
    __syncthreads();
    if (t < 8) {
        float L = l_s[0][t] + l_s[1][t] + l_s[2][t] + l_s[3][t];
        atomicAdd(&lg[b * 8 + t], L);
    }
}

// ---------------------------------------------------------------------------
// F2v: xbar = accg/lg, then om[b][h*64+d] = Wv_row(h,d) . xbar.
// grid 128 (b=blk>>3, h=blk&7), block 256.
__global__ __launch_bounds__(256) void ap_f2v(const float* __restrict__ accg,
                                              const float* __restrict__ lg,
                                              const float* __restrict__ Wkv,
                                              float* __restrict__ om) {
    __shared__ float4 xb_s[256];
    const int b = blockIdx.x >> 3, h = blockIdx.x & 7;
    const int t = threadIdx.x;
    const float inv = 1.f / lg[b * 8 + h];
    float4 a = ((const float4*)accg)[(b * 8 + h) * 256 + t];
    a.x *= inv; a.y *= inv; a.z *= inv; a.w *= inv;
    xb_s[t] = a;
    __syncthreads();

    const int d = t >> 2, qq = t & 3;
    const float4* W4 = (const float4*)Wkv + (long)(INNER + h * DIM_HEAD + d) * 256;
    float accv = 0.f;
#pragma unroll 8
    for (int j = 0; j < 64; ++j) {
        int idx = qq + 4 * j;
        float4 wv = W4[idx];
        float4 xv = xb_s[idx];
        accv += wv.x * xv.x + wv.y * xv.y + wv.z * xv.z + wv.w * xv.w;
    }
    accv += __shfl_xor(accv, 1);
    accv += __shfl_xor(accv, 2);
    if (qq == 0) om[b * INNER + h * DIM_HEAD + d] = accv;
}

// ---------------------------------------------------------------------------
// k5: out[b][e] = bo[e] + om[b] . Wo[e]   grid (16 chunks of 64 e, 16 b), block 256
__global__ void ap_k5_final(const float* __restrict__ Wo, const float* __restrict__ bo,
                            const float* __restrict__ om, float* __restrict__ out) {
    __shared__ float4 om_s[INNER / 4];
    const int chunk = blockIdx.x, b = blockIdx.y;
    const int t = threadIdx.x;
    if (t < 128) om_s[t] = ((const float4*)om)[b * (INNER / 4) + t];
    __syncthreads();
    const int eo = t >> 2, qq = t & 3;
    const int e = chunk * 64 + eo;
    const float4* W4 = (const float4*)Wo + (long)e * (INNER / 4);
    float acc = 0.f;
#pragma unroll 8
    for (int j = 0; j < 32; ++j) {
        int idx = qq + 4 * j;
        float4 w = W4[idx];
        float4 v = om_s[idx];
        acc += w.x * v.x + w.y * v.y + w.z * v.z + w.w * v.w;
    }
    acc += __shfl_xor(acc, 1);
    acc += __shfl_xor(acc, 2);
    if (qq == 0) out[b * EMBED + e] = acc + bo[e];
}

// ---------------------------------------------------------------------------
extern "C" void kernel_launch(void* const* d_in, const int* in_sizes, int n_in,
                              void* d_out, int out_size, void* d_ws, size_t ws_size,
                              hipStream_t stream) {
    const float* x     = (const float*)d_in[0];  // 16*2048*1024
    const float* token = (const float*)d_in[1];  // 1024
    const float* Wq    = (const float*)d_in[2];  // 512*1024
    const float* Wkv   = (const float*)d_in[3];  // 1024*1024
    const float* Wo    = (const float*)d_in[4];  // 1024*512
    const float* bo    = (const float*)d_in[5];  // 1024
    float* out = (float*)d_out;                  // 16*1024
    float* ws = (float*)d_ws;

    float* q          = ws + WS_Q;
    unsigned int* qkh = (unsigned int*)(ws + WS_QKB);
    float* accg       = ws + WS_ACC;
    float* lg         = ws + WS_LG;
    float* om         = ws + WS_OM;

    ap_zero<<<129, 256, 0, stream>>>(accg, 32800);   // accg + lg contiguous
    ap_f0a_q<<<64, 256, 0, stream>>>(token, Wq, q);
    ap_f0b_qk<<<64, 128, 0, stream>>>(q, Wkv, qkh);
    ap_f1<<<1024, 256, 0, stream>>>(x, qkh, accg, lg);
    ap_f2v<<<128, 256, 0, stream>>>(accg, lg, Wkv, om);
    ap_k5_final<<<dim3(16, 16), 256, 0, stream>>>(Wo, bo, om, out);
}

// Round 6
// 281.169 us; speedup vs baseline: 1.2106x; 1.2106x over previous
//
#include <hip/hip_runtime.h>

#define EMBED 1024
#define HEADS 8
#define DIM_HEAD 64
#define INNER 512
#define BATCH 16
#define SEQ 2048

// ws layout (floats):
#define WS_Q     0          // 512
#define WS_QKH   512        // 4096 uints = 8*1024 f16 (qk, pre-scaled by 0.125)
#define WS_PART  4608       // 16*64*8*1024 = 8388608 (per-slice partial sums)
#define WS_LP    8393216    // 16*64*8 = 8192 (per-slice l sums)
#define WS_OM    8401408    // 16*512
// total ~8.41M floats = ~33.6 MB

typedef _Float16 h2 __attribute__((ext_vector_type(2)));
union U2H { unsigned int u; h2 h; };

__device__ __forceinline__ h2 pk_f16(float a, float b) {
    return __builtin_bit_cast(h2, __builtin_amdgcn_cvt_pkrtz(a, b));
}

#if defined(__has_builtin)
#if __has_builtin(__builtin_amdgcn_fdot2)
#define FDOT2(a, b, c) __builtin_amdgcn_fdot2((a), (b), (c), false)
#endif
#endif
#ifndef FDOT2
__device__ __forceinline__ float fdot2_emul(h2 a, h2 b, float c) {
    return c + (float)a[0] * (float)b[0] + (float)a[1] * (float)b[1];
}
#define FDOT2(a, b, c) fdot2_emul((a), (b), (c))
#endif

// ---------------------------------------------------------------------------
// f0a: q[i] = token . Wq[i]  (512 dots of len 1024). grid 64, block 256.
__global__ void ap_f0a_q(const float* __restrict__ token, const float* __restrict__ Wq,
                         float* __restrict__ q) {
    const int t = threadIdx.x;
    const int w = t >> 6, lane = t & 63;
    const int i0 = blockIdx.x * 8 + w * 2;
    const float4* tok4 = (const float4*)token;
    const float4* r0 = (const float4*)Wq + (long)i0 * 256;
    const float4* r1 = r0 + 256;
    float a0 = 0.f, a1 = 0.f;
#pragma unroll
    for (int k = 0; k < 4; ++k) {
        int e4 = k * 64 + lane;
        float4 tv = tok4[e4];
        float4 w0 = r0[e4];
        float4 w1 = r1[e4];
        a0 += tv.x * w0.x + tv.y * w0.y + tv.z * w0.z + tv.w * w0.w;
        a1 += tv.x * w1.x + tv.y * w1.y + tv.z * w1.z + tv.w * w1.w;
    }
#pragma unroll
    for (int off = 32; off; off >>= 1) {
        a0 += __shfl_xor(a0, off);
        a1 += __shfl_xor(a1, off);
    }
    if (lane == 0) { q[i0] = a0; q[i0 + 1] = a1; }
}

// ---------------------------------------------------------------------------
// f0b: qk[h][e] = 0.125 * sum_d q[h*64+d] * Wk[h*64+d][e], packed to f16 pairs.
__global__ void ap_f0b_qk(const float* __restrict__ q, const float* __restrict__ Wkv,
                          unsigned int* __restrict__ qkh) {
    __shared__ float q_s[64];
    __shared__ float a_s[128];
    const int h = blockIdx.x >> 3, ec = blockIdx.x & 7;
    const int t = threadIdx.x;
    if (t < 64) q_s[t] = q[h * 64 + t];
    __syncthreads();
    const int e = ec * 128 + t;
    float a = 0.f;
#pragma unroll 8
    for (int d = 0; d < 64; ++d)
        a += q_s[d] * Wkv[(long)(h * 64 + d) * EMBED + e];
    a_s[t] = 0.125f * a;
    __syncthreads();
    if (t < 64) {
        U2H u;
        u.h = pk_f16(a_s[2 * t], a_s[2 * t + 1]);
        qkh[h * 512 + ec * 64 + t] = u.u;
    }
}

// ---------------------------------------------------------------------------
// F1: single pass over x. grid 1024 (b=blk>>6, slice=blk&63), block 256 = 4 waves.
// 32 rows/block, 4 tiles of 8 rows; wave computes sims for 2 rows (full e from
// registers, qk f16 in LDS, v_dot2), then after ONE barrier accumulates its
// 256-wide e-slice for all 8 heads from a global L2 re-read of the tile.
// Tail: plain coalesced per-block partial stores (NO atomics — R5 showed 64-way
// contended atomicAdd costs ~100us and 165MB of memory-side writes).
__global__ __launch_bounds__(256, 4) void ap_f1(const float* __restrict__ x,
                                                const unsigned int* __restrict__ qkh,
                                                float* __restrict__ partials,
                                                float* __restrict__ lpart) {
    __shared__ unsigned int qk_s[4096];          // 16 KB f16 qk
    __shared__ __align__(16) float p_s[2][8][8]; // double-buffered exp weights
    __shared__ float l_s[4][8];
    const int t = threadIdx.x;
    const int w = t >> 6, lane = t & 63, g = lane >> 3;
    const int b = blockIdx.x >> 6, slice = blockIdx.x & 63;

    ((uint4*)qk_s)[t]       = ((const uint4*)qkh)[t];
    ((uint4*)qk_s)[t + 256] = ((const uint4*)qkh)[t + 256];
    ((uint4*)qk_s)[t + 512] = ((const uint4*)qkh)[t + 512];
    ((uint4*)qk_s)[t + 768] = ((const uint4*)qkh)[t + 768];
    __syncthreads();

    const long rowbase = (long)b * SEQ + slice * 32;
    const float4* xg = (const float4*)x;

    float4 acc[8];
#pragma unroll
    for (int h = 0; h < 8; ++h) acc[h] = make_float4(0.f, 0.f, 0.f, 0.f);
    float lw = 0.f;

    // prefetch tile 0 sim rows (wave's 2 rows, full e)
    float4 xc0[4], xc1[4];
    {
        const float4* rp = xg + (rowbase + w * 2) * 256;
#pragma unroll
        for (int k = 0; k < 4; ++k) xc0[k] = rp[k * 64 + lane];
#pragma unroll
        for (int k = 0; k < 4; ++k) xc1[k] = rp[256 + k * 64 + lane];
    }

    for (int tile = 0; tile < 4; ++tile) {
        // prefetch next tile's sim rows
        float4 xn0[4], xn1[4];
        if (tile < 3) {
            const float4* rp = xg + (rowbase + (tile + 1) * 8 + w * 2) * 256;
#pragma unroll
            for (int k = 0; k < 4; ++k) xn0[k] = rp[k * 64 + lane];
#pragma unroll
            for (int k = 0; k < 4; ++k) xn1[k] = rp[256 + k * 64 + lane];
        }
        // early-issue acc loads for this tile (e-slice, L2-hot)
        float4 xa[8];
        {
            const float4* ap = xg + (rowbase + tile * 8) * 256 + w * 64 + lane;
#pragma unroll
            for (int r = 0; r < 8; ++r) xa[r] = ap[r * 256];
        }

        // sim compute on current rows (f16 dot2 against LDS qk)
        h2 c0[8], c1[8];
#pragma unroll
        for (int k = 0; k < 4; ++k) {
            c0[2 * k]     = pk_f16(xc0[k].x, xc0[k].y);
            c0[2 * k + 1] = pk_f16(xc0[k].z, xc0[k].w);
            c1[2 * k]     = pk_f16(xc1[k].x, xc1[k].y);
            c1[2 * k + 1] = pk_f16(xc1[k].z, xc1[k].w);
        }
        float s0[8], s1[8];
#pragma unroll
        for (int h = 0; h < 8; ++h) { s0[h] = 0.f; s1[h] = 0.f; }
#pragma unroll
        for (int k = 0; k < 4; ++k) {
#pragma unroll
            for (int h = 0; h < 8; ++h) {
                uint2 qu = *(const uint2*)&qk_s[h * 512 + k * 128 + lane * 2];
                U2H qa, qb; qa.u = qu.x; qb.u = qu.y;
                s0[h] = FDOT2(c0[2 * k], qa.h, s0[h]);
                s0[h] = FDOT2(c0[2 * k + 1], qb.h, s0[h]);
                s1[h] = FDOT2(c1[2 * k], qa.h, s1[h]);
                s1[h] = FDOT2(c1[2 * k + 1], qb.h, s1[h]);
            }
        }
        // 3 butterfly levels on all heads (reduce lane bits 5,4,3)
#pragma unroll
        for (int h = 0; h < 8; ++h) {
            s0[h] += __shfl_xor(s0[h], 32); s1[h] += __shfl_xor(s1[h], 32);
            s0[h] += __shfl_xor(s0[h], 16); s1[h] += __shfl_xor(s1[h], 16);
            s0[h] += __shfl_xor(s0[h], 8);  s1[h] += __shfl_xor(s1[h], 8);
        }
        // select head g per 8-lane group, finish reduction within the group
        float v0, v1;
        {
            float a0 = (g & 1) ? s0[1] : s0[0];
            float a1 = (g & 1) ? s0[3] : s0[2];
            float a2 = (g & 1) ? s0[5] : s0[4];
            float a3 = (g & 1) ? s0[7] : s0[6];
            float b0 = (g & 2) ? a1 : a0;
            float b1 = (g & 2) ? a3 : a2;
            v0 = (g & 4) ? b1 : b0;
            a0 = (g & 1) ? s1[1] : s1[0];
            a1 = (g & 1) ? s1[3] : s1[2];
            a2 = (g & 1) ? s1[5] : s1[4];
            a3 = (g & 1) ? s1[7] : s1[6];
            b0 = (g & 2) ? a1 : a0;
            b1 = (g & 2) ? a3 : a2;
            v1 = (g & 4) ? b1 : b0;
        }
        v0 += __shfl_xor(v0, 4); v1 += __shfl_xor(v1, 4);
        v0 += __shfl_xor(v0, 2); v1 += __shfl_xor(v1, 2);
        v0 += __shfl_xor(v0, 1); v1 += __shfl_xor(v1, 1);
        float p0 = __expf(v0), p1 = __expf(v1);
        lw += p0 + p1;
        if ((lane & 7) == 0) {
            p_s[tile & 1][w * 2][g] = p0;
            p_s[tile & 1][w * 2 + 1][g] = p1;
        }
        __syncthreads();

        // acc phase: wave's 256-wide e-slice, all 8 heads, 8 rows
#pragma unroll
        for (int r = 0; r < 8; ++r) {
            float4 pA = *(const float4*)&p_s[tile & 1][r][0];
            float4 pB = *(const float4*)&p_s[tile & 1][r][4];
            float4 xv = xa[r];
            acc[0].x += pA.x * xv.x; acc[0].y += pA.x * xv.y; acc[0].z += pA.x * xv.z; acc[0].w += pA.x * xv.w;
            acc[1].x += pA.y * xv.x; acc[1].y += pA.y * xv.y; acc[1].z += pA.y * xv.z; acc[1].w += pA.y * xv.w;
            acc[2].x += pA.z * xv.x; acc[2].y += pA.z * xv.y; acc[2].z += pA.z * xv.z; acc[2].w += pA.z * xv.w;
            acc[3].x += pA.w * xv.x; acc[3].y += pA.w * xv.y; acc[3].z += pA.w * xv.z; acc[3].w += pA.w * xv.w;
            acc[4].x += pB.x * xv.x; acc[4].y += pB.x * xv.y; acc[4].z += pB.x * xv.z; acc[4].w += pB.x * xv.w;
            acc[5].x += pB.y * xv.x; acc[5].y += pB.y * xv.y; acc[5].z += pB.y * xv.z; acc[5].w += pB.y * xv.w;
            acc[6].x += pB.z * xv.x; acc[6].y += pB.z * xv.y; acc[6].z += pB.z * xv.z; acc[6].w += pB.z * xv.w;
            acc[7].x += pB.w * xv.x; acc[7].y += pB.w * xv.y; acc[7].z += pB.w * xv.z; acc[7].w += pB.w * xv.w;
        }
        if (tile < 3) {
#pragma unroll
            for (int k = 0; k < 4; ++k) { xc0[k] = xn0[k]; xc1[k] = xn1[k]; }
        }
    }

    // per-block partial store (plain float4 stores, fully coalesced)
    float* base = partials + ((long)(b * 64 + slice) * 8) * 1024 + w * 256 + lane * 4;
#pragma unroll
    for (int h = 0; h < 8; ++h)
        *(float4*)(base + h * 1024) = acc[h];

    if ((lane & 7) == 0) l_s[w][g] = lw;
    __syncthreads();
    if (t < 8) {
        float L = l_s[0][t] + l_s[1][t] + l_s[2][t] + l_s[3][t];
        lpart[(b * 64 + slice) * 8 + t] = L;
    }
}

// ---------------------------------------------------------------------------
// F2v: combine 64 slice-partials -> xbar, then om[b][h*64+d] = Wv_row(h,d).xbar
// grid 128 (b=blk>>3, h=blk&7), block 256.
__global__ __launch_bounds__(256) void ap_f2v(const float* __restrict__ partials,
                                              const float* __restrict__ lpart,
                                              const float* __restrict__ Wkv,
                                              float* __restrict__ om) {
    __shared__ float4 xb_s[256];
    __shared__ float L_s;
    const int b = blockIdx.x >> 3, h = blockIdx.x & 7;
    const int t = threadIdx.x;

    // L = sum over 64 slices
    if (t < 64) {
        float v = lpart[(b * 64 + t) * 8 + h];
#pragma unroll
        for (int off = 32; off; off >>= 1) v += __shfl_xor(v, off);
        if (t == 0) L_s = v;
    }

    float4 a = make_float4(0.f, 0.f, 0.f, 0.f);
    const float4* pa = (const float4*)partials + ((long)(b * 64) * 8 + h) * 256 + t;
#pragma unroll 8
    for (int c = 0; c < 64; ++c) {
        float4 p = pa[(long)c * 8 * 256];
        a.x += p.x; a.y += p.y; a.z += p.z; a.w += p.w;
    }
    __syncthreads();
    const float inv = 1.f / L_s;
    a.x *= inv; a.y *= inv; a.z *= inv; a.w *= inv;
    xb_s[t] = a;
    __syncthreads();

    const int d = t >> 2, qq = t & 3;
    const float4* W4 = (const float4*)Wkv + (long)(INNER + h * DIM_HEAD + d) * 256;
    float accv = 0.f;
#pragma unroll 8
    for (int j = 0; j < 64; ++j) {
        int idx = qq + 4 * j;
        float4 wv = W4[idx];
        float4 xv = xb_s[idx];
        accv += wv.x * xv.x + wv.y * xv.y + wv.z * xv.z + wv.w * xv.w;
    }
    accv += __shfl_xor(accv, 1);
    accv += __shfl_xor(accv, 2);
    if (qq == 0) om[b * INNER + h * DIM_HEAD + d] = accv;
}

// ---------------------------------------------------------------------------
// k5: out[b][e] = bo[e] + om[b] . Wo[e]   grid (16 chunks of 64 e, 16 b), block 256
__global__ void ap_k5_final(const float* __restrict__ Wo, const float* __restrict__ bo,
                            const float* __restrict__ om, float* __restrict__ out) {
    __shared__ float4 om_s[INNER / 4];
    const int chunk = blockIdx.x, b = blockIdx.y;
    const int t = threadIdx.x;
    if (t < 128) om_s[t] = ((const float4*)om)[b * (INNER / 4) + t];
    __syncthreads();
    const int eo = t >> 2, qq = t & 3;
    const int e = chunk * 64 + eo;
    const float4* W4 = (const float4*)Wo + (long)e * (INNER / 4);
    float acc = 0.f;
#pragma unroll 8
    for (int j = 0; j < 32; ++j) {
        int idx = qq + 4 * j;
        float4 w = W4[idx];
        float4 v = om_s[idx];
        acc += w.x * v.x + w.y * v.y + w.z * v.z + w.w * v.w;
    }
    acc += __shfl_xor(acc, 1);
    acc += __shfl_xor(acc, 2);
    if (qq == 0) out[b * EMBED + e] = acc + bo[e];
}

// ---------------------------------------------------------------------------
extern "C" void kernel_launch(void* const* d_in, const int* in_sizes, int n_in,
                              void* d_out, int out_size, void* d_ws, size_t ws_size,
                              hipStream_t stream) {
    const float* x     = (const float*)d_in[0];  // 16*2048*1024
    const float* token = (const float*)d_in[1];  // 1024
    const float* Wq    = (const float*)d_in[2];  // 512*1024
    const float* Wkv   = (const float*)d_in[3];  // 1024*1024
    const float* Wo    = (const float*)d_in[4];  // 1024*512
    const float* bo    = (const float*)d_in[5];  // 1024
    float* out = (float*)d_out;                  // 16*1024
    float* ws = (float*)d_ws;

    float* q          = ws + WS_Q;
    unsigned int* qkh = (unsigned int*)(ws + WS_QKH);
    float* partials   = ws + WS_PART;
    float* lpart      = ws + WS_LP;
    float* om         = ws + WS_OM;

    ap_f0a_q<<<64, 256, 0, stream>>>(token, Wq, q);
    ap_f0b_qk<<<64, 128, 0, stream>>>(q, Wkv, qkh);
    ap_f1<<<1024, 256, 0, stream>>>(x, qkh, partials, lpart);
    ap_f2v<<<128, 256, 0, stream>>>(partials, lpart, Wkv, om);
    ap_k5_final<<<dim3(16, 16), 256, 0, stream>>>(Wo, bo, om, out);
}

// Round 7
// 237.406 us; speedup vs baseline: 1.4337x; 1.1843x over previous
//
#include <hip/hip_runtime.h>

#define EMBED 1024
#define HEADS 8
#define DIM_HEAD 64
#define INNER 512
#define BATCH 16
#define SEQ 2048

// ws layout (floats):
#define WS_Q     0          // 512
#define WS_QKH   512        // 4096 uints = 8*1024 f16 (qk, pre-scaled by 0.125)
#define WS_PART  4608       // 16*64*8*1024 = 8388608 (per-slice partial sums)
#define WS_LP    8393216    // 16*64*8 = 8192 (per-slice l sums)
#define WS_OM    8401408    // 16*512

typedef _Float16 h2 __attribute__((ext_vector_type(2)));
union U2H { unsigned int u; h2 h; };

__device__ __forceinline__ h2 pk_f16(float a, float b) {
    return __builtin_bit_cast(h2, __builtin_amdgcn_cvt_pkrtz(a, b));
}

#if defined(__has_builtin)
#if __has_builtin(__builtin_amdgcn_fdot2)
#define FDOT2(a, b, c) __builtin_amdgcn_fdot2((a), (b), (c), false)
#endif
#endif
#ifndef FDOT2
__device__ __forceinline__ float fdot2_emul(h2 a, h2 b, float c) {
    return c + (float)a[0] * (float)b[0] + (float)a[1] * (float)b[1];
}
#define FDOT2(a, b, c) fdot2_emul((a), (b), (c))
#endif

// ---------------------------------------------------------------------------
// f0a: q[i] = token . Wq[i]  (512 dots of len 1024). grid 64, block 256.
__global__ void ap_f0a_q(const float* __restrict__ token, const float* __restrict__ Wq,
                         float* __restrict__ q) {
    const int t = threadIdx.x;
    const int w = t >> 6, lane = t & 63;
    const int i0 = blockIdx.x * 8 + w * 2;
    const float4* tok4 = (const float4*)token;
    const float4* r0 = (const float4*)Wq + (long)i0 * 256;
    const float4* r1 = r0 + 256;
    float a0 = 0.f, a1 = 0.f;
#pragma unroll
    for (int k = 0; k < 4; ++k) {
        int e4 = k * 64 + lane;
        float4 tv = tok4[e4];
        float4 w0 = r0[e4];
        float4 w1 = r1[e4];
        a0 += tv.x * w0.x + tv.y * w0.y + tv.z * w0.z + tv.w * w0.w;
        a1 += tv.x * w1.x + tv.y * w1.y + tv.z * w1.z + tv.w * w1.w;
    }
#pragma unroll
    for (int off = 32; off; off >>= 1) {
        a0 += __shfl_xor(a0, off);
        a1 += __shfl_xor(a1, off);
    }
    if (lane == 0) { q[i0] = a0; q[i0 + 1] = a1; }
}

// ---------------------------------------------------------------------------
// f0b: qk[h][e] = 0.125 * sum_d q[h*64+d] * Wk[h*64+d][e], packed to f16 pairs.
__global__ void ap_f0b_qk(const float* __restrict__ q, const float* __restrict__ Wkv,
                          unsigned int* __restrict__ qkh) {
    __shared__ float q_s[64];
    __shared__ float a_s[128];
    const int h = blockIdx.x >> 3, ec = blockIdx.x & 7;
    const int t = threadIdx.x;
    if (t < 64) q_s[t] = q[h * 64 + t];
    __syncthreads();
    const int e = ec * 128 + t;
    float a = 0.f;
#pragma unroll 8
    for (int d = 0; d < 64; ++d)
        a += q_s[d] * Wkv[(long)(h * 64 + d) * EMBED + e];
    a_s[t] = 0.125f * a;
    __syncthreads();
    if (t < 64) {
        U2H u;
        u.h = pk_f16(a_s[2 * t], a_s[2 * t + 1]);
        qkh[h * 512 + ec * 64 + t] = u.u;
    }
}

// ---------------------------------------------------------------------------
// F1: single pass over x. grid 1024 (b=blk>>6, slice=blk&63), block 256 = 4 waves.
// 32 rows/block, 4 tiles of 8 rows; wave computes sims for 2 rows (f16 copies
// only — converted at load, 8 regs/row instead of 32 — vs qk f16 in LDS via
// v_dot2), then after ONE barrier accumulates its 256-wide e-slice for all 8
// heads, loading the tile rows directly from global (L2-hot re-read) inside
// the fma loop (no xa[] register array: R6 showed it spilled to scratch,
// +140MB HBM write traffic). Partial sums stored per-block, no atomics.
__global__ __launch_bounds__(256, 3) void ap_f1(const float* __restrict__ x,
                                                const unsigned int* __restrict__ qkh,
                                                float* __restrict__ partials,
                                                float* __restrict__ lpart) {
    __shared__ unsigned int qk_s[4096];          // 16 KB f16 qk
    __shared__ __align__(16) float p_s[2][8][8]; // double-buffered exp weights
    __shared__ float l_s[4][8];
    const int t = threadIdx.x;
    const int w = t >> 6, lane = t & 63, g = lane >> 3;
    const int b = blockIdx.x >> 6, slice = blockIdx.x & 63;

    ((uint4*)qk_s)[t]       = ((const uint4*)qkh)[t];
    ((uint4*)qk_s)[t + 256] = ((const uint4*)qkh)[t + 256];
    ((uint4*)qk_s)[t + 512] = ((const uint4*)qkh)[t + 512];
    ((uint4*)qk_s)[t + 768] = ((const uint4*)qkh)[t + 768];
    __syncthreads();

    const long rowbase = (long)b * SEQ + slice * 32;
    const float4* xg = (const float4*)x;

    float4 acc[8];
#pragma unroll
    for (int h = 0; h < 8; ++h) acc[h] = make_float4(0.f, 0.f, 0.f, 0.f);
    float lw = 0.f;

    // prefetch tile 0 sim rows, converting to f16 immediately (low reg cost)
    h2 cc0[8], cc1[8];
    {
        const float4* rp = xg + (rowbase + w * 2) * 256;
#pragma unroll
        for (int k = 0; k < 4; ++k) {
            float4 v = rp[k * 64 + lane];
            cc0[2 * k]     = pk_f16(v.x, v.y);
            cc0[2 * k + 1] = pk_f16(v.z, v.w);
        }
#pragma unroll
        for (int k = 0; k < 4; ++k) {
            float4 v = rp[256 + k * 64 + lane];
            cc1[2 * k]     = pk_f16(v.x, v.y);
            cc1[2 * k + 1] = pk_f16(v.z, v.w);
        }
    }

    for (int tile = 0; tile < 4; ++tile) {
        // prefetch next tile's sim rows (f16 form)
        h2 cn0[8], cn1[8];
        if (tile < 3) {
            const float4* rp = xg + (rowbase + (tile + 1) * 8 + w * 2) * 256;
#pragma unroll
            for (int k = 0; k < 4; ++k) {
                float4 v = rp[k * 64 + lane];
                cn0[2 * k]     = pk_f16(v.x, v.y);
                cn0[2 * k + 1] = pk_f16(v.z, v.w);
            }
#pragma unroll
            for (int k = 0; k < 4; ++k) {
                float4 v = rp[256 + k * 64 + lane];
                cn1[2 * k]     = pk_f16(v.x, v.y);
                cn1[2 * k + 1] = pk_f16(v.z, v.w);
            }
        }

        // sim compute on current rows (f16 dot2 against LDS qk)
        float s0[8], s1[8];
#pragma unroll
        for (int h = 0; h < 8; ++h) { s0[h] = 0.f; s1[h] = 0.f; }
#pragma unroll
        for (int k = 0; k < 4; ++k) {
#pragma unroll
            for (int h = 0; h < 8; ++h) {
                uint2 qu = *(const uint2*)&qk_s[h * 512 + k * 128 + lane * 2];
                U2H qa, qb; qa.u = qu.x; qb.u = qu.y;
                s0[h] = FDOT2(cc0[2 * k], qa.h, s0[h]);
                s0[h] = FDOT2(cc0[2 * k + 1], qb.h, s0[h]);
                s1[h] = FDOT2(cc1[2 * k], qa.h, s1[h]);
                s1[h] = FDOT2(cc1[2 * k + 1], qb.h, s1[h]);
            }
        }
        // 3 butterfly levels on all heads (reduce lane bits 5,4,3)
#pragma unroll
        for (int h = 0; h < 8; ++h) {
            s0[h] += __shfl_xor(s0[h], 32); s1[h] += __shfl_xor(s1[h], 32);
            s0[h] += __shfl_xor(s0[h], 16); s1[h] += __shfl_xor(s1[h], 16);
            s0[h] += __shfl_xor(s0[h], 8);  s1[h] += __shfl_xor(s1[h], 8);
        }
        // select head g per 8-lane group, finish reduction within the group
        float v0, v1;
        {
            float a0 = (g & 1) ? s0[1] : s0[0];
            float a1 = (g & 1) ? s0[3] : s0[2];
            float a2 = (g & 1) ? s0[5] : s0[4];
            float a3 = (g & 1) ? s0[7] : s0[6];
            float b0 = (g & 2) ? a1 : a0;
            float b1 = (g & 2) ? a3 : a2;
            v0 = (g & 4) ? b1 : b0;
            a0 = (g & 1) ? s1[1] : s1[0];
            a1 = (g & 1) ? s1[3] : s1[2];
            a2 = (g & 1) ? s1[5] : s1[4];
            a3 = (g & 1) ? s1[7] : s1[6];
            b0 = (g & 2) ? a1 : a0;
            b1 = (g & 2) ? a3 : a2;
            v1 = (g & 4) ? b1 : b0;
        }
        v0 += __shfl_xor(v0, 4); v1 += __shfl_xor(v1, 4);
        v0 += __shfl_xor(v0, 2); v1 += __shfl_xor(v1, 2);
        v0 += __shfl_xor(v0, 1); v1 += __shfl_xor(v1, 1);
        float p0 = __expf(v0), p1 = __expf(v1);
        lw += p0 + p1;
        if ((lane & 7) == 0) {
            p_s[tile & 1][w * 2][g] = p0;
            p_s[tile & 1][w * 2 + 1][g] = p1;
        }
        __syncthreads();

        // acc phase: wave's 256-wide e-slice, all 8 heads, 8 rows.
        // Loads issued inside the loop (L2-hot; hidden by 12 waves/CU).
        const float4* ap = xg + (rowbase + tile * 8) * 256 + w * 64 + lane;
#pragma unroll
        for (int r = 0; r < 8; ++r) {
            float4 xv = ap[r * 256];
            float4 pA = *(const float4*)&p_s[tile & 1][r][0];
            float4 pB = *(const float4*)&p_s[tile & 1][r][4];
            acc[0].x += pA.x * xv.x; acc[0].y += pA.x * xv.y; acc[0].z += pA.x * xv.z; acc[0].w += pA.x * xv.w;
            acc[1].x += pA.y * xv.x; acc[1].y += pA.y * xv.y; acc[1].z += pA.y * xv.z; acc[1].w += pA.y * xv.w;
            acc[2].x += pA.z * xv.x; acc[2].y += pA.z * xv.y; acc[2].z += pA.z * xv.z; acc[2].w += pA.z * xv.w;
            acc[3].x += pA.w * xv.x; acc[3].y += pA.w * xv.y; acc[3].z += pA.w * xv.z; acc[3].w += pA.w * xv.w;
            acc[4].x += pB.x * xv.x; acc[4].y += pB.x * xv.y; acc[4].z += pB.x * xv.z; acc[4].w += pB.x * xv.w;
            acc[5].x += pB.y * xv.x; acc[5].y += pB.y * xv.y; acc[5].z += pB.y * xv.z; acc[5].w += pB.y * xv.w;
            acc[6].x += pB.z * xv.x; acc[6].y += pB.z * xv.y; acc[6].z += pB.z * xv.z; acc[6].w += pB.z * xv.w;
            acc[7].x += pB.w * xv.x; acc[7].y += pB.w * xv.y; acc[7].z += pB.w * xv.z; acc[7].w += pB.w * xv.w;
        }
        if (tile < 3) {
#pragma unroll
            for (int k = 0; k < 8; ++k) { cc0[k] = cn0[k]; cc1[k] = cn1[k]; }
        }
    }

    // per-block partial store (plain float4 stores, fully coalesced)
    float* base = partials + ((long)(b * 64 + slice) * 8) * 1024 + w * 256 + lane * 4;
#pragma unroll
    for (int h = 0; h < 8; ++h)
        *(float4*)(base + h * 1024) = acc[h];

    if ((lane & 7) == 0) l_s[w][g] = lw;
    __syncthreads();
    if (t < 8) {
        float L = l_s[0][t] + l_s[1][t] + l_s[2][t] + l_s[3][t];
        lpart[(b * 64 + slice) * 8 + t] = L;
    }
}

// ---------------------------------------------------------------------------
// F2v: combine 64 slice-partials -> xbar, then om[b][h*64+d] = Wv_row(h,d).xbar
// grid 128 (b=blk>>3, h=blk&7), block 256.
__global__ __launch_bounds__(256) void ap_f2v(const float* __restrict__ partials,
                                              const float* __restrict__ lpart,
                                              const float* __restrict__ Wkv,
                                              float* __restrict__ om) {
    __shared__ float4 xb_s[256];
    __shared__ float L_s;
    const int b = blockIdx.x >> 3, h = blockIdx.x & 7;
    const int t = threadIdx.x;

    // L = sum over 64 slices
    if (t < 64) {
        float v = lpart[(b * 64 + t) * 8 + h];
#pragma unroll
        for (int off = 32; off; off >>= 1) v += __shfl_xor(v, off);
        if (t == 0) L_s = v;
    }

    float4 a = make_float4(0.f, 0.f, 0.f, 0.f);
    const float4* pa = (const float4*)partials + ((long)(b * 64) * 8 + h) * 256 + t;
#pragma unroll 8
    for (int c = 0; c < 64; ++c) {
        float4 p = pa[(long)c * 8 * 256];
        a.x += p.x; a.y += p.y; a.z += p.z; a.w += p.w;
    }
    __syncthreads();
    const float inv = 1.f / L_s;
    a.x *= inv; a.y *= inv; a.z *= inv; a.w *= inv;
    xb_s[t] = a;
    __syncthreads();

    const int d = t >> 2, qq = t & 3;
    const float4* W4 = (const float4*)Wkv + (long)(INNER + h * DIM_HEAD + d) * 256;
    float accv = 0.f;
#pragma unroll 8
    for (int j = 0; j < 64; ++j) {
        int idx = qq + 4 * j;
        float4 wv = W4[idx];
        float4 xv = xb_s[idx];
        accv += wv.x * xv.x + wv.y * xv.y + wv.z * xv.z + wv.w * xv.w;
    }
    accv += __shfl_xor(accv, 1);
    accv += __shfl_xor(accv, 2);
    if (qq == 0) om[b * INNER + h * DIM_HEAD + d] = accv;
}

// ---------------------------------------------------------------------------
// k5: out[b][e] = bo[e] + om[b] . Wo[e]   grid (16 chunks of 64 e, 16 b), block 256
__global__ void ap_k5_final(const float* __restrict__ Wo, const float* __restrict__ bo,
                            const float* __restrict__ om, float* __restrict__ out) {
    __shared__ float4 om_s[INNER / 4];
    const int chunk = blockIdx.x, b = blockIdx.y;
    const int t = threadIdx.x;
    if (t < 128) om_s[t] = ((const float4*)om)[b * (INNER / 4) + t];
    __syncthreads();
    const int eo = t >> 2, qq = t & 3;
    const int e = chunk * 64 + eo;
    const float4* W4 = (const float4*)Wo + (long)e * (INNER / 4);
    float acc = 0.f;
#pragma unroll 8
    for (int j = 0; j < 32; ++j) {
        int idx = qq + 4 * j;
        float4 w = W4[idx];
        float4 v = om_s[idx];
        acc += w.x * v.x + w.y * v.y + w.z * v.z + w.w * v.w;
    }
    acc += __shfl_xor(acc, 1);
    acc += __shfl_xor(acc, 2);
    if (qq == 0) out[b * EMBED + e] = acc + bo[e];
}

// ---------------------------------------------------------------------------
extern "C" void kernel_launch(void* const* d_in, const int* in_sizes, int n_in,
                              void* d_out, int out_size, void* d_ws, size_t ws_size,
                              hipStream_t stream) {
    const float* x     = (const float*)d_in[0];  // 16*2048*1024
    const float* token = (const float*)d_in[1];  // 1024
    const float* Wq    = (const float*)d_in[2];  // 512*1024
    const float* Wkv   = (const float*)d_in[3];  // 1024*1024
    const float* Wo    = (const float*)d_in[4];  // 1024*512
    const float* bo    = (const float*)d_in[5];  // 1024
    float* out = (float*)d_out;                  // 16*1024
    float* ws = (float*)d_ws;

    float* q          = ws + WS_Q;
    unsigned int* qkh = (unsigned int*)(ws + WS_QKH);
    float* partials   = ws + WS_PART;
    float* lpart      = ws + WS_LP;
    float* om         = ws + WS_OM;

    ap_f0a_q<<<64, 256, 0, stream>>>(token, Wq, q);
    ap_f0b_qk<<<64, 128, 0, stream>>>(q, Wkv, qkh);
    ap_f1<<<1024, 256, 0, stream>>>(x, qkh, partials, lpart);
    ap_f2v<<<128, 256, 0, stream>>>(partials, lpart, Wkv, om);
    ap_k5_final<<<dim3(16, 16), 256, 0, stream>>>(Wo, bo, om, out);
}